// Round 3
// baseline (3380.470 us; speedup 1.0000x reference)
//
#include <hip/hip_runtime.h>
#include <stdint.h>

typedef unsigned short u16;
typedef __bf16 bf16x8 __attribute__((ext_vector_type(8)));
typedef float f32x4 __attribute__((ext_vector_type(4)));
typedef unsigned short u16x8 __attribute__((ext_vector_type(8)));
typedef unsigned short u16x4 __attribute__((ext_vector_type(4)));

#define SK_EPS 1e-8f
#define S_T 20.60992915555662f   /* log2(e)/0.07 */
#define S_S 14.426950408889634f  /* log2(e)/0.1  */
#define INV_TT 14.285714285714286f
#define INV_TS 10.0f

__device__ __forceinline__ float b2f(u16 u){ return __uint_as_float(((unsigned)u)<<16); }
__device__ __forceinline__ u16 f2b(float f){
  unsigned u = __float_as_uint(f);
  u += 0x7FFFu + ((u>>16)&1u);   // RNE truncate to bf16 (finite data)
  return (u16)(u>>16);
}
__device__ __forceinline__ unsigned encf(float x){ unsigned u=__float_as_uint(x); return (u&0x80000000u)? ~u : (u|0x80000000u); }
__device__ __forceinline__ float decf(unsigned u){ return (u&0x80000000u)? __uint_as_float(u&0x7FFFFFFFu) : __uint_as_float(~u); }

__device__ __forceinline__ void gload16(const void* g, void* l){
  __builtin_amdgcn_global_load_lds((const __attribute__((address_space(1))) void*)g,
                                   (__attribute__((address_space(3))) void*)l, 16, 0, 0);
}

// ---------------- row normalize + bf16 cast ----------------
__global__ __launch_bounds__(192) void norm_cast(const float* __restrict__ in, u16* __restrict__ out,
                                                 u16* __restrict__ out2, int donorm){
  int row = blockIdx.x, tid = threadIdx.x;
  const float4* p = (const float4*)(in + (size_t)row*768);
  float4 v = p[tid];
  float ss = v.x*v.x + v.y*v.y + v.z*v.z + v.w*v.w;
  #pragma unroll
  for (int off=1; off<64; off<<=1) ss += __shfl_xor(ss, off);
  __shared__ float smem[3];
  int wv = tid>>6;
  if ((tid&63)==0) smem[wv] = ss;
  __syncthreads();
  float tot = smem[0]+smem[1]+smem[2];
  float scale = donorm ? (1.0f/fmaxf(sqrtf(tot), 1e-12f)) : 1.0f;
  u16x4 o;
  o[0]=f2b(v.x); o[1]=f2b(v.y); o[2]=f2b(v.z); o[3]=f2b(v.w);
  u16x4 on;
  on[0]=f2b(v.x*scale); on[1]=f2b(v.y*scale); on[2]=f2b(v.z*scale); on[3]=f2b(v.w*scale);
  if (out2){
    *(u16x4*)(out  + (size_t)row*768 + tid*4) = o;
    *(u16x4*)(out2 + (size_t)row*768 + tid*4) = on;
  } else {
    *(u16x4*)(out + (size_t)row*768 + tid*4) = donorm ? on : o;
  }
}

// ---------------- GEMM: C[M,N] = A[M,Kd]*B[N,Kd]^T, 256x256 tile, 512 thr ----
// BK=32, double-buffered 64 KiB LDS -> 2 blocks/CU.
// LDS layout per buffer: A region [4 k-halves][256 rows] of 16B slots (conflict-free
// ds_read_b128: lane l reads slot (l>>4)*256 + row), B region identical.
// MODE 0: store bf16 C + fused Sinkhorn col-sum atomics
// MODE 1: student epilogue -> sexp[m] += sum exp(s/Ts); sdot[m] += b3*sum(Q~*s)
// MODE 2: koleo epilogue -> maxd[m] = max off-diag dot (encoded uint)
template<int MODE>
__global__ __launch_bounds__(512, 4) void gemm_bt(
    const u16* __restrict__ A, const u16* __restrict__ B, int Ndim, int Kd,
    u16* __restrict__ Cout, float* __restrict__ colC,
    const u16* __restrict__ Tl, const float* __restrict__ a3, const float* __restrict__ b3,
    float* __restrict__ sexp, float* __restrict__ sdot, unsigned* __restrict__ maxd)
{
  __shared__ __align__(16) u16 lds[32768];   // 64 KiB: 2 bufs x (A 16K + B 16K)
  int tid = threadIdx.x, lane = tid & 63, wave = tid >> 6;
  int wr = wave >> 2, wc = wave & 3;         // 2M x 4N waves, wave-tile 128x64

  // XCD-aware supertile mapping
  int bid = blockIdx.x, tm, tn;
  if (gridDim.x == 1024){
    int xcd = bid & 7, local = bid >> 3;
    int g = local >> 4, w = local & 15;
    tn = g*4 + (w & 3);
    tm = xcd*4 + (w >> 2);
  } else { int nbn = Ndim >> 8; tm = bid / nbn; tn = bid % nbn; }
  int m0 = tm << 8, n0 = tn << 8;

  const f32x4 fzero = {0.f,0.f,0.f,0.f};
  f32x4 acc[8][4];
  #pragma unroll
  for (int i=0;i<8;++i)
    #pragma unroll
    for (int j=0;j<4;++j) acc[i][j] = fzero;

  const int nkt = Kd >> 5;                   // 24 K-steps of 32
  // stage tile kt into buffer p: 4 gloads/thread (2 A + 2 B)
  auto stage = [&](int p, int kt){
    int k0 = kt << 5;
    int pbase = p << 14;                     // p*16384 elements
    #pragma unroll
    for (int i=0;i<2;++i){
      int sb = i*512 + (wave<<6);            // uniform slot base (64 slots/instr)
      int h  = sb >> 8;                      // k-half 0..3 (8 elems = 16B)
      int rb = sb & 255;                     // row base
      gload16(A + (size_t)(m0 + rb + lane)*Kd + k0 + h*8,
              (void*)(lds + pbase + sb*8));
      gload16(B + (size_t)(n0 + rb + lane)*Kd + k0 + h*8,
              (void*)(lds + pbase + 8192 + sb*8));
    }
  };

  stage(0, 0);
  int p = 0;
  int h = lane >> 4;                         // this lane's k-half for frag reads
  for (int kt=0; kt<nkt; ++kt){
    if (kt+1 < nkt){
      stage(p^1, kt+1);
      asm volatile("s_waitcnt vmcnt(4)" ::: "memory");  // wait only current tile
    } else {
      asm volatile("s_waitcnt vmcnt(0)" ::: "memory");
    }
    __builtin_amdgcn_s_barrier();
    __builtin_amdgcn_sched_barrier(0);
    const u16* As = lds + (p<<14);
    const u16* Bs = As + 8192;
    bf16x8 af[8], bfr[4];
    #pragma unroll
    for (int f=0; f<8; ++f){
      int r = (wr<<7) + (f<<4) + (lane&15);
      af[f] = *(const bf16x8*)(const void*)(As + (h<<11) + (r<<3));
    }
    #pragma unroll
    for (int g=0; g<4; ++g){
      int c = (wc<<6) + (g<<4) + (lane&15);
      bfr[g] = *(const bf16x8*)(const void*)(Bs + (h<<11) + (c<<3));
    }
    __builtin_amdgcn_s_setprio(1);
    #pragma unroll
    for (int fm=0;fm<8;++fm)
      #pragma unroll
      for (int fn=0;fn<4;++fn)
        acc[fm][fn] = __builtin_amdgcn_mfma_f32_16x16x32_bf16(af[fm], bfr[fn], acc[fm][fn], 0,0,0);
    __builtin_amdgcn_s_setprio(0);
    __builtin_amdgcn_sched_barrier(0);
    __builtin_amdgcn_s_barrier();
    p ^= 1;
  }

  if constexpr (MODE == 0){
    float cs[4] = {0.f,0.f,0.f,0.f};
    #pragma unroll
    for (int fm=0;fm<8;++fm)
      #pragma unroll
      for (int j=0;j<4;++j){
        size_t gr = (size_t)(m0 + (wr<<7)+(fm<<4)+((lane>>4)<<2)+j);
        #pragma unroll
        for (int fn=0;fn<4;++fn){
          int cl = (wc<<6)+(fn<<4)+(lane&15);
          u16 hb = f2b(acc[fm][fn][j]);
          Cout[gr*(size_t)Ndim + n0+cl] = hb;
          cs[fn] += exp2f(b2f(hb)*S_T);
        }
      }
    #pragma unroll
    for (int fn=0;fn<4;++fn){
      float v = cs[fn];
      v += __shfl_xor(v,16); v += __shfl_xor(v,32);
      if (lane < 16) atomicAdd(&colC[n0 + (wc<<6)+(fn<<4)+lane], v);
    }
  } else if constexpr (MODE == 1){
    // Re-read Tl C-tile in two 64 KiB halves (rows 0-127, 128-255)
    __syncthreads();
    #pragma unroll
    for (int half=0; half<2; ++half){
      // stage half: 4096 slots, 8 gloads/thread, layout [128][256] u16 linear
      #pragma unroll
      for (int i=0;i<8;++i){
        int sb = i*512 + (wave<<6);          // uniform; 64 slots = 2 rows of 32 slots
        int row = sb >> 5;
        int cc0 = sb & 31;
        gload16(Tl + (size_t)(m0 + half*128 + row + (lane>>5))*Ndim + n0 + ((cc0 + (lane&31))&31)*8
                   + ((lane>>5) ? 0 : 0),
                (void*)(lds + sb*8));
      }
      asm volatile("s_waitcnt vmcnt(0)" ::: "memory");
      __syncthreads();
      if (wr == half){
        #pragma unroll
        for (int fm=0;fm<8;++fm)
          #pragma unroll
          for (int j=0;j<4;++j){
            int lrow = (fm<<4)+((lane>>4)<<2)+j;            // 0..127 within half
            size_t gr = (size_t)(m0 + (wr<<7) + lrow);
            float sx=0.f, sd=0.f;
            #pragma unroll
            for (int fn=0;fn<4;++fn){
              int cl = (wc<<6)+(fn<<4)+(lane&15);
              size_t gc = (size_t)(n0+cl);
              float v = acc[fm][fn][j];
              float tl = b2f(lds[(size_t)lrow*256 + cl]);
              sx += exp2f(v*S_S);
              sd += exp2f(tl*S_T)*a3[gc]*v;
            }
            #pragma unroll
            for (int off=1; off<16; off<<=1){ sx += __shfl_xor(sx,off); sd += __shfl_xor(sd,off); }
            if ((lane&15)==0){
              atomicAdd(&sexp[gr], sx);
              atomicAdd(&sdot[gr], b3[gr]*sd);
            }
          }
      }
      __syncthreads();
    }
  } else {
    #pragma unroll
    for (int fm=0;fm<8;++fm)
      #pragma unroll
      for (int j=0;j<4;++j){
        size_t gr = (size_t)(m0 + (wr<<7)+(fm<<4)+((lane>>4)<<2)+j);
        float mx = -2.0f;
        #pragma unroll
        for (int fn=0;fn<4;++fn){
          int cl = (wc<<6)+(fn<<4)+(lane&15);
          size_t gc = (size_t)(n0+cl);
          float v = acc[fm][fn][j];
          if (gr != gc) mx = fmaxf(mx, v);
        }
        #pragma unroll
        for (int off=1; off<16; off<<=1) mx = fmaxf(mx, __shfl_xor(mx,off));
        if ((lane&15)==0) atomicMax(&maxd[gr], encf(mx));
      }
  }
}

// ---------------- Sinkhorn passes over t_logits (bf16 [M,K]) ----------------
__global__ __launch_bounds__(256) void sk_colsum(const u16* __restrict__ L, const float* __restrict__ bvec,
                                                 float* __restrict__ colOut, int Kc, int useb){
  int tid = threadIdx.x;
  int c0 = blockIdx.x*2048 + tid*8;
  int r0 = blockIdx.y*64;
  float acc[8] = {0.f,0.f,0.f,0.f,0.f,0.f,0.f,0.f};
  for (int r=r0; r<r0+64; ++r){
    u16x8 v = *(const u16x8*)(L + (size_t)r*Kc + c0);
    float bm = useb ? bvec[r] : 1.0f;
    #pragma unroll
    for (int i=0;i<8;++i) acc[i] += exp2f(b2f(v[i])*S_T)*bm;
  }
  #pragma unroll
  for (int i=0;i<8;++i) atomicAdd(&colOut[c0+i], acc[i]);
}

__global__ __launch_bounds__(256) void sk_rowsum(const u16* __restrict__ L, const float* __restrict__ avec,
    float* __restrict__ rowR, float* __restrict__ rowRE, float* __restrict__ rowT, int Kc, int mode){
  int m = blockIdx.x, tid = threadIdx.x;
  const u16* Lr = L + (size_t)m*Kc;
  float sR=0.f, sRE=0.f, sT=0.f;
  int nit = Kc/2048;
  for (int it=0; it<nit; ++it){
    int c = it*2048 + tid*8;
    u16x8 v = *(const u16x8*)(Lr + c);
    f32x4 alo = *(const f32x4*)(avec+c);
    f32x4 ahi = *(const f32x4*)(avec+c+4);
    #pragma unroll
    for (int i=0;i<8;++i){
      float l = b2f(v[i]);
      float E = exp2f(l*S_T);
      float a = (i<4)? alo[i] : ahi[i-4];
      float Ea = E*a;
      sR += Ea;
      if (mode&1) sRE += E;
      if (mode&2) sT += Ea*l;
    }
  }
  #pragma unroll
  for (int off=1; off<64; off<<=1){
    sR += __shfl_xor(sR,off);
    sRE += __shfl_xor(sRE,off);
    sT += __shfl_xor(sT,off);
  }
  __shared__ float red[3][4];
  int wv = tid>>6;
  if ((tid&63)==0){ red[0][wv]=sR; red[1][wv]=sRE; red[2][wv]=sT; }
  __syncthreads();
  if (tid==0){
    rowR[m] = red[0][0]+red[0][1]+red[0][2]+red[0][3];
    if (mode&1) rowRE[m] = red[1][0]+red[1][1]+red[1][2]+red[1][3];
    if (mode&2) rowT[m]  = red[2][0]+red[2][1]+red[2][2]+red[2][3];
  }
}

__global__ void upd_col(float* aV, float* colC, int K, int first){
  int k = blockIdx.x*256+threadIdx.x;
  if (k<K){
    float s = colC[k];
    float p = first ? 1.0f : aV[k];
    aV[k] = p/(p*s + SK_EPS);
    colC[k] = 0.0f;
  }
}
__global__ void upd_row(float* bV, const float* rowR, int M, int first){
  int m = blockIdx.x*256+threadIdx.x;
  if (m<M){
    float R = rowR[m];
    float p = first ? 1.0f : bV[m];
    bV[m] = p/(p*R + SK_EPS);
  }
}
__global__ void fin_rows(float* bV, const float* rowR, const float* rowRE, const float* rowT,
                         float* sumQ, float* ttok, int M){
  int m = blockIdx.x*256+threadIdx.x;
  if (m<M){
    float p = bV[m], R = rowR[m];
    float b3 = p/(p*R + SK_EPS);
    bV[m] = b3;
    float sq = b3*R;
    sumQ[m] = sq;
    ttok[m] = logf(rowRE[m])*sq - b3*rowT[m]*INV_TT;
  }
}

// ---------------- final reduce ----------------
__global__ __launch_bounds__(1024) void finalize(const unsigned char* __restrict__ mask,
    const float* __restrict__ sexp, const float* __restrict__ sdot,
    const float* __restrict__ sumQ, const float* __restrict__ ttok,
    const unsigned* __restrict__ maxd, float* __restrict__ out, int M, int K){
  int tid = threadIdx.x;
  __shared__ int isBool;
  if (tid==0) isBool = 0;
  __syncthreads();
  int f = 0;
  for (int i=tid; i<M; i+=1024) if ((i&3) && mask[i]) f = 1;
  if (f) isBool = 1;
  __syncthreads();
  int ib = isBool;
  float cn=0.f, cc=0.f, ts=0.f, ks=0.f;
  for (int m=tid; m<M; m+=1024){
    int mk = ib ? (mask[m]!=0) : (((const int*)mask)[m]!=0);
    float pt = logf(sexp[m])*sumQ[m] - sdot[m]*INV_TS;
    if (mk){ cn += pt; cc += 1.0f; }
    ts += ttok[m];
  }
  for (int k=tid; k<K; k+=1024){
    float d = decf(maxd[k]);
    ks += logf(sqrtf(fmaxf(2.0f-2.0f*d, 0.0f)) + SK_EPS);
  }
  #pragma unroll
  for (int off=1; off<64; off<<=1){
    cn += __shfl_xor(cn,off); cc += __shfl_xor(cc,off);
    ts += __shfl_xor(ts,off); ks += __shfl_xor(ks,off);
  }
  __shared__ float red[4][16];
  int wv = tid>>6;
  if ((tid&63)==0){ red[0][wv]=cn; red[1][wv]=cc; red[2][wv]=ts; red[3][wv]=ks; }
  __syncthreads();
  if (tid==0){
    float CN=0,CC=0,TS=0,KS=0;
    for (int i=0;i<16;++i){ CN+=red[0][i]; CC+=red[1][i]; TS+=red[2][i]; KS+=red[3][i]; }
    out[0] = CN/fmaxf(CC,1.0f);
    out[1] = TS/(float)M;
    out[2] = -KS/(float)K;
  }
}

extern "C" void kernel_launch(void* const* d_in, const int* in_sizes, int n_in,
                              void* d_out, int out_size, void* d_ws, size_t ws_size,
                              hipStream_t stream){
  const float* teacher = (const float*)d_in[0];
  const float* student = (const float*)d_in[1];
  const unsigned char* mask = (const unsigned char*)d_in[2];
  const float* proto = (const float*)d_in[3];
  const int D = 768;
  const int M = in_sizes[0]/D;   // 8192
  const int K = in_sizes[3]/D;   // 8192
  float* out = (float*)d_out;

  char* ws = (char*)d_ws;
  size_t off = 0;
  auto alloc = [&](size_t bytes)->void*{ void* p = ws+off; off += (bytes+255)&~(size_t)255; return p; };
  u16* t_logits = (u16*)alloc((size_t)M*K*2);
  u16* t_hat    = (u16*)alloc((size_t)M*D*2);
  u16* s_hat    = (u16*)alloc((size_t)M*D*2);
  u16* w_bf     = (u16*)alloc((size_t)K*D*2);
  u16* w_hat    = (u16*)alloc((size_t)K*D*2);
  float* colC   = (float*)alloc((size_t)K*4);
  float* sexp   = (float*)alloc((size_t)M*4);
  float* sdot   = (float*)alloc((size_t)M*4);
  unsigned* maxd= (unsigned*)alloc((size_t)K*4);
  float* aV     = (float*)alloc((size_t)K*4);
  float* bV     = (float*)alloc((size_t)M*4);
  float* rowR   = (float*)alloc((size_t)M*4);
  float* rowRE  = (float*)alloc((size_t)M*4);
  float* rowT   = (float*)alloc((size_t)M*4);
  float* sumQ   = (float*)alloc((size_t)M*4);
  float* ttok   = (float*)alloc((size_t)M*4);

  hipMemsetAsync(colC, 0, (size_t)K*4, stream);
  hipMemsetAsync(sexp, 0, (size_t)M*4, stream);
  hipMemsetAsync(sdot, 0, (size_t)M*4, stream);
  hipMemsetAsync(maxd, 0, (size_t)K*4, stream);

  norm_cast<<<M, 192, 0, stream>>>(teacher, t_hat, nullptr, 1);
  norm_cast<<<M, 192, 0, stream>>>(student, s_hat, nullptr, 1);
  norm_cast<<<K, 192, 0, stream>>>(proto, w_bf, w_hat, 1);

  int nblk = (M/256)*(K/256);    // 1024
  gemm_bt<0><<<nblk, 512, 0, stream>>>(t_hat, w_bf, K, D, t_logits, colC,
                                       nullptr,nullptr,nullptr,nullptr,nullptr,nullptr);

  dim3 cgrid(K/2048, M/64);
  // SK iter 1 (col-sum fused above)
  upd_col<<<(K+255)/256, 256, 0, stream>>>(aV, colC, K, 1);
  sk_rowsum<<<M, 256, 0, stream>>>(t_logits, aV, rowR, rowRE, rowT, K, 1);
  upd_row<<<(M+255)/256, 256, 0, stream>>>(bV, rowR, M, 1);
  // SK iter 2
  sk_colsum<<<cgrid, 256, 0, stream>>>(t_logits, bV, colC, K, 1);
  upd_col<<<(K+255)/256, 256, 0, stream>>>(aV, colC, K, 0);
  sk_rowsum<<<M, 256, 0, stream>>>(t_logits, aV, rowR, rowRE, rowT, K, 0);
  upd_row<<<(M+255)/256, 256, 0, stream>>>(bV, rowR, M, 0);
  // SK iter 3
  sk_colsum<<<cgrid, 256, 0, stream>>>(t_logits, bV, colC, K, 1);
  upd_col<<<(K+255)/256, 256, 0, stream>>>(aV, colC, K, 0);
  sk_rowsum<<<M, 256, 0, stream>>>(t_logits, aV, rowR, rowRE, rowT, K, 2);
  fin_rows<<<(M+255)/256, 256, 0, stream>>>(bV, rowR, rowRE, rowT, sumQ, ttok, M);

  gemm_bt<1><<<nblk, 512, 0, stream>>>(s_hat, w_bf, K, D, nullptr, nullptr,
                                       t_logits, aV, bV, sexp, sdot, nullptr);
  gemm_bt<2><<<nblk, 512, 0, stream>>>(w_hat, w_hat, K, D, nullptr, nullptr,
                                       nullptr,nullptr,nullptr,nullptr,nullptr, maxd);

  finalize<<<1, 1024, 0, stream>>>(mask, sexp, sdot, sumQ, ttok, maxd, out, M, K);
}

// Round 4
// 1116.003 us; speedup vs baseline: 3.0291x; 3.0291x over previous
//
#include <hip/hip_runtime.h>
#include <stdint.h>

typedef unsigned short u16;
typedef __bf16 bf16x8 __attribute__((ext_vector_type(8)));
typedef float f32x4 __attribute__((ext_vector_type(4)));
typedef unsigned short u16x8 __attribute__((ext_vector_type(8)));
typedef unsigned short u16x4 __attribute__((ext_vector_type(4)));

#define SK_EPS 1e-8f
#define S_T 20.60992915555662f   /* log2(e)/0.07 */
#define S_S 14.426950408889634f  /* log2(e)/0.1  */
#define INV_TT 14.285714285714286f
#define INV_TS 10.0f

__device__ __forceinline__ float b2f(u16 u){ return __uint_as_float(((unsigned)u)<<16); }
__device__ __forceinline__ u16 f2b(float f){
  unsigned u = __float_as_uint(f);
  u += 0x7FFFu + ((u>>16)&1u);   // RNE truncate to bf16 (finite data)
  return (u16)(u>>16);
}
__device__ __forceinline__ unsigned encf(float x){ unsigned u=__float_as_uint(x); return (u&0x80000000u)? ~u : (u|0x80000000u); }
__device__ __forceinline__ float decf(unsigned u){ return (u&0x80000000u)? __uint_as_float(u&0x7FFFFFFFu) : __uint_as_float(~u); }

__device__ __forceinline__ void gload16(const void* g, void* l){
  __builtin_amdgcn_global_load_lds((const __attribute__((address_space(1))) void*)g,
                                   (__attribute__((address_space(3))) void*)l, 16, 0, 0);
}

// ---------------- row normalize + bf16 cast ----------------
__global__ __launch_bounds__(192) void norm_cast(const float* __restrict__ in, u16* __restrict__ out,
                                                 u16* __restrict__ out2, int donorm){
  int row = blockIdx.x, tid = threadIdx.x;
  const float4* p = (const float4*)(in + (size_t)row*768);
  float4 v = p[tid];
  float ss = v.x*v.x + v.y*v.y + v.z*v.z + v.w*v.w;
  #pragma unroll
  for (int off=1; off<64; off<<=1) ss += __shfl_xor(ss, off);
  __shared__ float smem[3];
  int wv = tid>>6;
  if ((tid&63)==0) smem[wv] = ss;
  __syncthreads();
  float tot = smem[0]+smem[1]+smem[2];
  float scale = donorm ? (1.0f/fmaxf(sqrtf(tot), 1e-12f)) : 1.0f;
  u16x4 o;
  o[0]=f2b(v.x); o[1]=f2b(v.y); o[2]=f2b(v.z); o[3]=f2b(v.w);
  u16x4 on;
  on[0]=f2b(v.x*scale); on[1]=f2b(v.y*scale); on[2]=f2b(v.z*scale); on[3]=f2b(v.w*scale);
  if (out2){
    *(u16x4*)(out  + (size_t)row*768 + tid*4) = o;
    *(u16x4*)(out2 + (size_t)row*768 + tid*4) = on;
  } else {
    *(u16x4*)(out + (size_t)row*768 + tid*4) = donorm ? on : o;
  }
}

// ---------------- GEMM: C[M,N] = A[M,Kd]*B[N,Kd]^T, 256x256 tile, 512 thr ----
// BK=32, double-buffered 64 KiB LDS -> 2 blocks/CU. launch_bounds min-waves=2
// (NOT 4: min-waves=4 caps the unified VGPR+AGPR budget below acc[8][4]'s
// 128 AGPRs and spills accumulators to scratch -- round-3 regression).
// LDS layout per buffer: [4 k-halves][256 rows] of 16B slots, conflict-free
// ds_read_b128 (lane l reads slot (l>>4)*256 + row).
template<int MODE>
__global__ __launch_bounds__(512, 2) void gemm_bt(
    const u16* __restrict__ A, const u16* __restrict__ B, int Ndim, int Kd,
    u16* __restrict__ Cout, float* __restrict__ colC,
    const u16* __restrict__ Tl, const float* __restrict__ a3, const float* __restrict__ b3,
    float* __restrict__ sexp, float* __restrict__ sdot, unsigned* __restrict__ maxd)
{
  __shared__ __align__(16) u16 lds[32768];   // 64 KiB: 2 bufs x (A 16K + B 16K)
  int tid = threadIdx.x, lane = tid & 63, wave = tid >> 6;
  int wr = wave >> 2, wc = wave & 3;         // 2M x 4N waves, wave-tile 128x64

  // XCD-aware supertile mapping
  int bid = blockIdx.x, tm, tn;
  if (gridDim.x == 1024){
    int xcd = bid & 7, local = bid >> 3;
    int g = local >> 4, w = local & 15;
    tn = g*4 + (w & 3);
    tm = xcd*4 + (w >> 2);
  } else { int nbn = Ndim >> 8; tm = bid / nbn; tn = bid % nbn; }
  int m0 = tm << 8, n0 = tn << 8;

  const f32x4 fzero = {0.f,0.f,0.f,0.f};
  f32x4 acc[8][4];
  #pragma unroll
  for (int i=0;i<8;++i)
    #pragma unroll
    for (int j=0;j<4;++j) acc[i][j] = fzero;

  const int nkt = Kd >> 5;                   // 24 K-steps of 32
  auto stage = [&](int p, int kt){
    int k0 = kt << 5;
    int pbase = p << 14;                     // p*16384 elements
    #pragma unroll
    for (int i=0;i<2;++i){
      int sb = i*512 + (wave<<6);            // uniform slot base (64 slots/instr)
      int h  = sb >> 8;                      // k-half 0..3 (8 elems = 16B)
      int rb = sb & 255;                     // row base
      gload16(A + (size_t)(m0 + rb + lane)*Kd + k0 + h*8,
              (void*)(lds + pbase + sb*8));
      gload16(B + (size_t)(n0 + rb + lane)*Kd + k0 + h*8,
              (void*)(lds + pbase + 8192 + sb*8));
    }
  };

  stage(0, 0);
  int p = 0;
  int h = lane >> 4;                         // this lane's k-half for frag reads
  for (int kt=0; kt<nkt; ++kt){
    if (kt+1 < nkt){
      stage(p^1, kt+1);
      asm volatile("s_waitcnt vmcnt(4)" ::: "memory");  // wait only current tile
    } else {
      asm volatile("s_waitcnt vmcnt(0)" ::: "memory");
    }
    __builtin_amdgcn_s_barrier();
    __builtin_amdgcn_sched_barrier(0);
    const u16* As = lds + (p<<14);
    const u16* Bs = As + 8192;
    bf16x8 af[8], bfr[4];
    #pragma unroll
    for (int f=0; f<8; ++f){
      int r = (wr<<7) + (f<<4) + (lane&15);
      af[f] = *(const bf16x8*)(const void*)(As + (h<<11) + (r<<3));
    }
    #pragma unroll
    for (int g=0; g<4; ++g){
      int c = (wc<<6) + (g<<4) + (lane&15);
      bfr[g] = *(const bf16x8*)(const void*)(Bs + (h<<11) + (c<<3));
    }
    __builtin_amdgcn_s_setprio(1);
    #pragma unroll
    for (int fm=0;fm<8;++fm)
      #pragma unroll
      for (int fn=0;fn<4;++fn)
        acc[fm][fn] = __builtin_amdgcn_mfma_f32_16x16x32_bf16(af[fm], bfr[fn], acc[fm][fn], 0,0,0);
    __builtin_amdgcn_s_setprio(0);
    __builtin_amdgcn_sched_barrier(0);
    __builtin_amdgcn_s_barrier();
    p ^= 1;
  }

  if constexpr (MODE == 0){
    float cs[4] = {0.f,0.f,0.f,0.f};
    #pragma unroll
    for (int fm=0;fm<8;++fm)
      #pragma unroll
      for (int j=0;j<4;++j){
        size_t gr = (size_t)(m0 + (wr<<7)+(fm<<4)+((lane>>4)<<2)+j);
        #pragma unroll
        for (int fn=0;fn<4;++fn){
          int cl = (wc<<6)+(fn<<4)+(lane&15);
          u16 hb = f2b(acc[fm][fn][j]);
          Cout[gr*(size_t)Ndim + n0+cl] = hb;
          cs[fn] += exp2f(b2f(hb)*S_T);
        }
      }
    #pragma unroll
    for (int fn=0;fn<4;++fn){
      float v = cs[fn];
      v += __shfl_xor(v,16); v += __shfl_xor(v,32);
      if (lane < 16) atomicAdd(&colC[n0 + (wc<<6)+(fn<<4)+lane], v);
    }
  } else if constexpr (MODE == 1){
    // Re-read Tl C-tile in two 64 KiB halves (rows 0-127, 128-255)
    __syncthreads();
    #pragma unroll
    for (int half=0; half<2; ++half){
      #pragma unroll
      for (int i=0;i<8;++i){
        int sb = i*512 + (wave<<6);          // uniform; 64 slots = 2 rows of 32 slots
        int row = sb >> 5;
        gload16(Tl + (size_t)(m0 + half*128 + row + (lane>>5))*Ndim + n0 + (lane&31)*8,
                (void*)(lds + sb*8));
      }
      asm volatile("s_waitcnt vmcnt(0)" ::: "memory");
      __syncthreads();
      if (wr == half){
        #pragma unroll
        for (int fm=0;fm<8;++fm)
          #pragma unroll
          for (int j=0;j<4;++j){
            int lrow = (fm<<4)+((lane>>4)<<2)+j;            // 0..127 within half
            size_t gr = (size_t)(m0 + (wr<<7) + lrow);
            float sx=0.f, sd=0.f;
            #pragma unroll
            for (int fn=0;fn<4;++fn){
              int cl = (wc<<6)+(fn<<4)+(lane&15);
              size_t gc = (size_t)(n0+cl);
              float v = acc[fm][fn][j];
              float tl = b2f(lds[(size_t)lrow*256 + cl]);
              sx += exp2f(v*S_S);
              sd += exp2f(tl*S_T)*a3[gc]*v;
            }
            #pragma unroll
            for (int off=1; off<16; off<<=1){ sx += __shfl_xor(sx,off); sd += __shfl_xor(sd,off); }
            if ((lane&15)==0){
              atomicAdd(&sexp[gr], sx);
              atomicAdd(&sdot[gr], b3[gr]*sd);
            }
          }
      }
      __syncthreads();
    }
  } else {
    #pragma unroll
    for (int fm=0;fm<8;++fm)
      #pragma unroll
      for (int j=0;j<4;++j){
        size_t gr = (size_t)(m0 + (wr<<7)+(fm<<4)+((lane>>4)<<2)+j);
        float mx = -2.0f;
        #pragma unroll
        for (int fn=0;fn<4;++fn){
          int cl = (wc<<6)+(fn<<4)+(lane&15);
          size_t gc = (size_t)(n0+cl);
          float v = acc[fm][fn][j];
          if (gr != gc) mx = fmaxf(mx, v);
        }
        #pragma unroll
        for (int off=1; off<16; off<<=1) mx = fmaxf(mx, __shfl_xor(mx,off));
        if ((lane&15)==0) atomicMax(&maxd[gr], encf(mx));
      }
  }
}

// ---------------- Sinkhorn passes over t_logits (bf16 [M,K]) ----------------
__global__ __launch_bounds__(256) void sk_colsum(const u16* __restrict__ L, const float* __restrict__ bvec,
                                                 float* __restrict__ colOut, int Kc, int useb){
  int tid = threadIdx.x;
  int c0 = blockIdx.x*2048 + tid*8;
  int r0 = blockIdx.y*64;
  float acc[8] = {0.f,0.f,0.f,0.f,0.f,0.f,0.f,0.f};
  for (int r=r0; r<r0+64; ++r){
    u16x8 v = *(const u16x8*)(L + (size_t)r*Kc + c0);
    float bm = useb ? bvec[r] : 1.0f;
    #pragma unroll
    for (int i=0;i<8;++i) acc[i] += exp2f(b2f(v[i])*S_T)*bm;
  }
  #pragma unroll
  for (int i=0;i<8;++i) atomicAdd(&colOut[c0+i], acc[i]);
}

__global__ __launch_bounds__(256) void sk_rowsum(const u16* __restrict__ L, const float* __restrict__ avec,
    float* __restrict__ rowR, float* __restrict__ rowRE, float* __restrict__ rowT, int Kc, int mode){
  int m = blockIdx.x, tid = threadIdx.x;
  const u16* Lr = L + (size_t)m*Kc;
  float sR=0.f, sRE=0.f, sT=0.f;
  int nit = Kc/2048;
  for (int it=0; it<nit; ++it){
    int c = it*2048 + tid*8;
    u16x8 v = *(const u16x8*)(Lr + c);
    f32x4 alo = *(const f32x4*)(avec+c);
    f32x4 ahi = *(const f32x4*)(avec+c+4);
    #pragma unroll
    for (int i=0;i<8;++i){
      float l = b2f(v[i]);
      float E = exp2f(l*S_T);
      float a = (i<4)? alo[i] : ahi[i-4];
      float Ea = E*a;
      sR += Ea;
      if (mode&1) sRE += E;
      if (mode&2) sT += Ea*l;
    }
  }
  #pragma unroll
  for (int off=1; off<64; off<<=1){
    sR += __shfl_xor(sR,off);
    sRE += __shfl_xor(sRE,off);
    sT += __shfl_xor(sT,off);
  }
  __shared__ float red[3][4];
  int wv = tid>>6;
  if ((tid&63)==0){ red[0][wv]=sR; red[1][wv]=sRE; red[2][wv]=sT; }
  __syncthreads();
  if (tid==0){
    rowR[m] = red[0][0]+red[0][1]+red[0][2]+red[0][3];
    if (mode&1) rowRE[m] = red[1][0]+red[1][1]+red[1][2]+red[1][3];
    if (mode&2) rowT[m]  = red[2][0]+red[2][1]+red[2][2]+red[2][3];
  }
}

__global__ void upd_col(float* aV, float* colC, int K, int first){
  int k = blockIdx.x*256+threadIdx.x;
  if (k<K){
    float s = colC[k];
    float p = first ? 1.0f : aV[k];
    aV[k] = p/(p*s + SK_EPS);
    colC[k] = 0.0f;
  }
}
__global__ void upd_row(float* bV, const float* rowR, int M, int first){
  int m = blockIdx.x*256+threadIdx.x;
  if (m<M){
    float R = rowR[m];
    float p = first ? 1.0f : bV[m];
    bV[m] = p/(p*R + SK_EPS);
  }
}
__global__ void fin_rows(float* bV, const float* rowR, const float* rowRE, const float* rowT,
                         float* sumQ, float* ttok, int M){
  int m = blockIdx.x*256+threadIdx.x;
  if (m<M){
    float p = bV[m], R = rowR[m];
    float b3 = p/(p*R + SK_EPS);
    bV[m] = b3;
    float sq = b3*R;
    sumQ[m] = sq;
    ttok[m] = logf(rowRE[m])*sq - b3*rowT[m]*INV_TT;
  }
}

// ---------------- final reduce ----------------
__global__ __launch_bounds__(1024) void finalize(const unsigned char* __restrict__ mask,
    const float* __restrict__ sexp, const float* __restrict__ sdot,
    const float* __restrict__ sumQ, const float* __restrict__ ttok,
    const unsigned* __restrict__ maxd, float* __restrict__ out, int M, int K){
  int tid = threadIdx.x;
  __shared__ int isBool;
  if (tid==0) isBool = 0;
  __syncthreads();
  int f = 0;
  for (int i=tid; i<M; i+=1024) if ((i&3) && mask[i]) f = 1;
  if (f) isBool = 1;
  __syncthreads();
  int ib = isBool;
  float cn=0.f, cc=0.f, ts=0.f, ks=0.f;
  for (int m=tid; m<M; m+=1024){
    int mk = ib ? (mask[m]!=0) : (((const int*)mask)[m]!=0);
    float pt = logf(sexp[m])*sumQ[m] - sdot[m]*INV_TS;
    if (mk){ cn += pt; cc += 1.0f; }
    ts += ttok[m];
  }
  for (int k=tid; k<K; k+=1024){
    float d = decf(maxd[k]);
    ks += logf(sqrtf(fmaxf(2.0f-2.0f*d, 0.0f)) + SK_EPS);
  }
  #pragma unroll
  for (int off=1; off<64; off<<=1){
    cn += __shfl_xor(cn,off); cc += __shfl_xor(cc,off);
    ts += __shfl_xor(ts,off); ks += __shfl_xor(ks,off);
  }
  __shared__ float red[4][16];
  int wv = tid>>6;
  if ((tid&63)==0){ red[0][wv]=cn; red[1][wv]=cc; red[2][wv]=ts; red[3][wv]=ks; }
  __syncthreads();
  if (tid==0){
    float CN=0,CC=0,TS=0,KS=0;
    for (int i=0;i<16;++i){ CN+=red[0][i]; CC+=red[1][i]; TS+=red[2][i]; KS+=red[3][i]; }
    out[0] = CN/fmaxf(CC,1.0f);
    out[1] = TS/(float)M;
    out[2] = -KS/(float)K;
  }
}

extern "C" void kernel_launch(void* const* d_in, const int* in_sizes, int n_in,
                              void* d_out, int out_size, void* d_ws, size_t ws_size,
                              hipStream_t stream){
  const float* teacher = (const float*)d_in[0];
  const float* student = (const float*)d_in[1];
  const unsigned char* mask = (const unsigned char*)d_in[2];
  const float* proto = (const float*)d_in[3];
  const int D = 768;
  const int M = in_sizes[0]/D;   // 8192
  const int K = in_sizes[3]/D;   // 8192
  float* out = (float*)d_out;

  char* ws = (char*)d_ws;
  size_t off = 0;
  auto alloc = [&](size_t bytes)->void*{ void* p = ws+off; off += (bytes+255)&~(size_t)255; return p; };
  u16* t_logits = (u16*)alloc((size_t)M*K*2);
  u16* t_hat    = (u16*)alloc((size_t)M*D*2);
  u16* s_hat    = (u16*)alloc((size_t)M*D*2);
  u16* w_bf     = (u16*)alloc((size_t)K*D*2);
  u16* w_hat    = (u16*)alloc((size_t)K*D*2);
  float* colC   = (float*)alloc((size_t)K*4);
  float* sexp   = (float*)alloc((size_t)M*4);
  float* sdot   = (float*)alloc((size_t)M*4);
  unsigned* maxd= (unsigned*)alloc((size_t)K*4);
  float* aV     = (float*)alloc((size_t)K*4);
  float* bV     = (float*)alloc((size_t)M*4);
  float* rowR   = (float*)alloc((size_t)M*4);
  float* rowRE  = (float*)alloc((size_t)M*4);
  float* rowT   = (float*)alloc((size_t)M*4);
  float* sumQ   = (float*)alloc((size_t)M*4);
  float* ttok   = (float*)alloc((size_t)M*4);

  hipMemsetAsync(colC, 0, (size_t)K*4, stream);
  hipMemsetAsync(sexp, 0, (size_t)M*4, stream);
  hipMemsetAsync(sdot, 0, (size_t)M*4, stream);
  hipMemsetAsync(maxd, 0, (size_t)K*4, stream);

  norm_cast<<<M, 192, 0, stream>>>(teacher, t_hat, nullptr, 1);
  norm_cast<<<M, 192, 0, stream>>>(student, s_hat, nullptr, 1);
  norm_cast<<<K, 192, 0, stream>>>(proto, w_bf, w_hat, 1);

  int nblk = (M/256)*(K/256);    // 1024
  gemm_bt<0><<<nblk, 512, 0, stream>>>(t_hat, w_bf, K, D, t_logits, colC,
                                       nullptr,nullptr,nullptr,nullptr,nullptr,nullptr);

  dim3 cgrid(K/2048, M/64);
  // SK iter 1 (col-sum fused above)
  upd_col<<<(K+255)/256, 256, 0, stream>>>(aV, colC, K, 1);
  sk_rowsum<<<M, 256, 0, stream>>>(t_logits, aV, rowR, rowRE, rowT, K, 1);
  upd_row<<<(M+255)/256, 256, 0, stream>>>(bV, rowR, M, 1);
  // SK iter 2
  sk_colsum<<<cgrid, 256, 0, stream>>>(t_logits, bV, colC, K, 1);
  upd_col<<<(K+255)/256, 256, 0, stream>>>(aV, colC, K, 0);
  sk_rowsum<<<M, 256, 0, stream>>>(t_logits, aV, rowR, rowRE, rowT, K, 0);
  upd_row<<<(M+255)/256, 256, 0, stream>>>(bV, rowR, M, 0);
  // SK iter 3
  sk_colsum<<<cgrid, 256, 0, stream>>>(t_logits, bV, colC, K, 1);
  upd_col<<<(K+255)/256, 256, 0, stream>>>(aV, colC, K, 0);
  sk_rowsum<<<M, 256, 0, stream>>>(t_logits, aV, rowR, rowRE, rowT, K, 2);
  fin_rows<<<(M+255)/256, 256, 0, stream>>>(bV, rowR, rowRE, rowT, sumQ, ttok, M);

  gemm_bt<1><<<nblk, 512, 0, stream>>>(s_hat, w_bf, K, D, nullptr, nullptr,
                                       t_logits, aV, bV, sexp, sdot, nullptr);
  gemm_bt<2><<<nblk, 512, 0, stream>>>(w_hat, w_hat, K, D, nullptr, nullptr,
                                       nullptr,nullptr,nullptr,nullptr,nullptr, maxd);

  finalize<<<1, 1024, 0, stream>>>(mask, sexp, sdot, sumQ, ttok, maxd, out, M, K);
}

// Round 6
// 733.547 us; speedup vs baseline: 4.6084x; 1.5214x over previous
//
#include <hip/hip_runtime.h>
#include <stdint.h>

typedef unsigned short u16;
typedef __bf16 bf16x8 __attribute__((ext_vector_type(8)));
typedef float f32x4 __attribute__((ext_vector_type(4)));
typedef unsigned short u16x8 __attribute__((ext_vector_type(8)));
typedef unsigned short u16x4 __attribute__((ext_vector_type(4)));

#define SK_EPS 1e-8f
#define S_T 20.60992915555662f   /* log2(e)/0.07 */
#define S_S 14.426950408889634f  /* log2(e)/0.1  */
#define INV_TT 14.285714285714286f
#define INV_TS 10.0f

__device__ __forceinline__ float b2f(u16 u){ return __uint_as_float(((unsigned)u)<<16); }
__device__ __forceinline__ u16 f2b(float f){
  unsigned u = __float_as_uint(f);
  u += 0x7FFFu + ((u>>16)&1u);   // RNE truncate to bf16 (finite data)
  return (u16)(u>>16);
}
__device__ __forceinline__ unsigned encf(float x){ unsigned u=__float_as_uint(x); return (u&0x80000000u)? ~u : (u|0x80000000u); }
__device__ __forceinline__ float decf(unsigned u){ return (u&0x80000000u)? __uint_as_float(u&0x7FFFFFFFu) : __uint_as_float(~u); }

__device__ __forceinline__ void gload16(const void* g, void* l){
  __builtin_amdgcn_global_load_lds((const __attribute__((address_space(1))) void*)g,
                                   (__attribute__((address_space(3))) void*)l, 16, 0, 0);
}

// ---------------- row normalize + bf16 cast ----------------
__global__ __launch_bounds__(192) void norm_cast(const float* __restrict__ in, u16* __restrict__ out,
                                                 u16* __restrict__ out2, int donorm){
  int row = blockIdx.x, tid = threadIdx.x;
  const float4* p = (const float4*)(in + (size_t)row*768);
  float4 v = p[tid];
  float ss = v.x*v.x + v.y*v.y + v.z*v.z + v.w*v.w;
  #pragma unroll
  for (int off=1; off<64; off<<=1) ss += __shfl_xor(ss, off);
  __shared__ float smem[3];
  int wv = tid>>6;
  if ((tid&63)==0) smem[wv] = ss;
  __syncthreads();
  float tot = smem[0]+smem[1]+smem[2];
  float scale = donorm ? (1.0f/fmaxf(sqrtf(tot), 1e-12f)) : 1.0f;
  u16x4 o;
  o[0]=f2b(v.x); o[1]=f2b(v.y); o[2]=f2b(v.z); o[3]=f2b(v.w);
  u16x4 on;
  on[0]=f2b(v.x*scale); on[1]=f2b(v.y*scale); on[2]=f2b(v.z*scale); on[3]=f2b(v.w*scale);
  if (out2){
    *(u16x4*)(out  + (size_t)row*768 + tid*4) = o;
    *(u16x4*)(out2 + (size_t)row*768 + tid*4) = on;
  } else {
    *(u16x4*)(out + (size_t)row*768 + tid*4) = donorm ? on : o;
  }
}

// ---------------- GEMM: C[M,N] = A[M,Kd]*B[N,Kd]^T, 128x128 tile, 256 thr ----
// Round-1 proven structure: single-buffered 32 KiB LDS, XOR-swizzled staging
// (0 bank conflicts), acc[4][4] (64 AGPR) + ~80 VGPR -> ~3 blocks/CU; implicit
// cross-block overlap hides the drain-barrier (m97 regime).
// + XCD supertile: each XCD owns 8 tile-rows; sweep 8-col groups (A,B panels
//   1.6 MB each -> L2-resident per XCD).
// MODE 0: store bf16 C + fused Sinkhorn col-sum atomics
// MODE 1: student epilogue -> sexp[m] += sum exp(s/Ts); sdot[m] += b3*sum(Q~*s)
// MODE 2: koleo epilogue -> maxd[m] = max off-diag dot (encoded uint)
template<int MODE>
__global__ __launch_bounds__(256) void gemm_bt(
    const u16* __restrict__ A, const u16* __restrict__ B, int Ndim, int Kd,
    u16* __restrict__ Cout, float* __restrict__ colC,
    const u16* __restrict__ Tl, const float* __restrict__ a3, const float* __restrict__ b3,
    float* __restrict__ sexp, float* __restrict__ sdot, unsigned* __restrict__ maxd)
{
  __shared__ __align__(16) u16 As[128*64];
  __shared__ __align__(16) u16 Bs[128*64];
  int tid = threadIdx.x, lane = tid & 63, wave = tid >> 6;
  int wr = wave >> 1, wc = wave & 1;

  // XCD supertile mapping for the 64x64 tile grid
  int bid = blockIdx.x, tm, tn;
  if (gridDim.x == 4096){
    int xcd = bid & 7, local = bid >> 3;   // 0..511
    int g = local >> 6, w = local & 63;    // 8 col-groups x (8x8 supertile)
    tm = xcd*8 + (w >> 3);
    tn = g*8 + (w & 7);
  } else { int nbn = Ndim >> 7; tm = bid / nbn; tn = bid % nbn; }
  int m0 = tm<<7, n0 = tn<<7;

  const f32x4 fzero = {0.f,0.f,0.f,0.f};
  f32x4 acc[4][4];
  #pragma unroll
  for (int i=0;i<4;++i)
    #pragma unroll
    for (int j=0;j<4;++j) acc[i][j] = fzero;

  int srcRow = lane>>3;                       // row within 8-row chunk
  int srcCol = (((lane&7) ^ (lane>>3)) << 3); // XOR-swizzled source column

  int nkt = Kd>>6;
  for (int kt=0; kt<nkt; ++kt){
    if (kt) __syncthreads();
    int k0 = kt<<6;
    #pragma unroll
    for (int c=0;c<4;++c){
      int chunk = (wave<<2)+c;
      int row = (chunk<<3) + srcRow;
      gload16(A + (size_t)(m0+row)*Kd + k0 + srcCol, (void*)(As + (chunk<<9)));
      gload16(B + (size_t)(n0+row)*Kd + k0 + srcCol, (void*)(Bs + (chunk<<9)));
    }
    asm volatile("s_waitcnt vmcnt(0)" ::: "memory");
    __syncthreads();
    #pragma unroll
    for (int ks=0; ks<2; ++ks){
      bf16x8 af[4], bfr[4];
      #pragma unroll
      for (int f=0; f<4; ++f){
        int rowA = (wr<<6)+(f<<4)+(lane&15);
        int idxA = ((rowA<<6) + (ks<<5) + ((lane>>4)<<3)) ^ ((lane&7)<<3);
        af[f] = *(const bf16x8*)(const void*)(As + idxA);
        int rowB = (wc<<6)+(f<<4)+(lane&15);
        int idxB = ((rowB<<6) + (ks<<5) + ((lane>>4)<<3)) ^ ((lane&7)<<3);
        bfr[f] = *(const bf16x8*)(const void*)(Bs + idxB);
      }
      #pragma unroll
      for (int fm=0;fm<4;++fm)
        #pragma unroll
        for (int fn=0;fn<4;++fn)
          acc[fm][fn] = __builtin_amdgcn_mfma_f32_16x16x32_bf16(af[fm], bfr[fn], acc[fm][fn], 0,0,0);
    }
  }

  if constexpr (MODE == 0){
    float cs[4] = {0.f,0.f,0.f,0.f};
    #pragma unroll
    for (int fm=0;fm<4;++fm)
      #pragma unroll
      for (int j=0;j<4;++j){
        size_t gr = (size_t)(m0 + (wr<<6)+(fm<<4)+((lane>>4)<<2)+j);
        #pragma unroll
        for (int fn=0;fn<4;++fn){
          int cl = (wc<<6)+(fn<<4)+(lane&15);
          u16 hb = f2b(acc[fm][fn][j]);
          Cout[gr*(size_t)Ndim + n0+cl] = hb;
          cs[fn] += exp2f(b2f(hb)*S_T);
        }
      }
    // per-column totals over this wave's 64 rows: reduce lane>>4 groups
    #pragma unroll
    for (int fn=0;fn<4;++fn){
      float v = cs[fn];
      v += __shfl_xor(v,16); v += __shfl_xor(v,32);
      if (lane < 16) atomicAdd(&colC[n0 + (wc<<6)+(fn<<4)+lane], v);
    }
  } else if constexpr (MODE == 1){
    #pragma unroll
    for (int fm=0;fm<4;++fm)
      #pragma unroll
      for (int j=0;j<4;++j){
        size_t gr = (size_t)(m0 + (wr<<6)+(fm<<4)+((lane>>4)<<2)+j);
        float sx=0.f, sd=0.f;
        #pragma unroll
        for (int fn=0;fn<4;++fn){
          int cl = (wc<<6)+(fn<<4)+(lane&15);
          size_t gc = (size_t)(n0+cl);
          float v = acc[fm][fn][j];
          float tl = b2f(Tl[gr*(size_t)Ndim + gc]);
          sx += exp2f(v*S_S);
          sd += exp2f(tl*S_T)*a3[gc]*v;
        }
        #pragma unroll
        for (int off=1; off<16; off<<=1){ sx += __shfl_xor(sx,off); sd += __shfl_xor(sd,off); }
        if ((lane&15)==0){
          atomicAdd(&sexp[gr], sx);
          atomicAdd(&sdot[gr], b3[gr]*sd);
        }
      }
  } else {
    #pragma unroll
    for (int fm=0;fm<4;++fm)
      #pragma unroll
      for (int j=0;j<4;++j){
        size_t gr = (size_t)(m0 + (wr<<6)+(fm<<4)+((lane>>4)<<2)+j);
        float mx = -2.0f;
        #pragma unroll
        for (int fn=0;fn<4;++fn){
          int cl = (wc<<6)+(fn<<4)+(lane&15);
          size_t gc = (size_t)(n0+cl);
          float v = acc[fm][fn][j];
          if (gr != gc) mx = fmaxf(mx, v);
        }
        #pragma unroll
        for (int off=1; off<16; off<<=1) mx = fmaxf(mx, __shfl_xor(mx,off));
        if ((lane&15)==0) atomicMax(&maxd[gr], encf(mx));
      }
  }
}

// ---------------- Sinkhorn passes over t_logits (bf16 [M,K]) ----------------
__global__ __launch_bounds__(256) void sk_colsum(const u16* __restrict__ L, const float* __restrict__ bvec,
                                                 float* __restrict__ colOut, int Kc, int useb){
  int tid = threadIdx.x;
  int c0 = blockIdx.x*2048 + tid*8;
  int r0 = blockIdx.y*64;
  float acc[8] = {0.f,0.f,0.f,0.f,0.f,0.f,0.f,0.f};
  for (int r=r0; r<r0+64; ++r){
    u16x8 v = *(const u16x8*)(L + (size_t)r*Kc + c0);
    float bm = useb ? bvec[r] : 1.0f;
    #pragma unroll
    for (int i=0;i<8;++i) acc[i] += exp2f(b2f(v[i])*S_T)*bm;
  }
  #pragma unroll
  for (int i=0;i<8;++i) atomicAdd(&colOut[c0+i], acc[i]);
}

__global__ __launch_bounds__(256) void sk_rowsum(const u16* __restrict__ L, const float* __restrict__ avec,
    float* __restrict__ rowR, float* __restrict__ rowRE, float* __restrict__ rowT, int Kc, int mode){
  int m = blockIdx.x, tid = threadIdx.x;
  const u16* Lr = L + (size_t)m*Kc;
  float sR=0.f, sRE=0.f, sT=0.f;
  int nit = Kc/2048;
  for (int it=0; it<nit; ++it){
    int c = it*2048 + tid*8;
    u16x8 v = *(const u16x8*)(Lr + c);
    f32x4 alo = *(const f32x4*)(avec+c);
    f32x4 ahi = *(const f32x4*)(avec+c+4);
    #pragma unroll
    for (int i=0;i<8;++i){
      float l = b2f(v[i]);
      float E = exp2f(l*S_T);
      float a = (i<4)? alo[i] : ahi[i-4];
      float Ea = E*a;
      sR += Ea;
      if (mode&1) sRE += E;
      if (mode&2) sT += Ea*l;
    }
  }
  #pragma unroll
  for (int off=1; off<64; off<<=1){
    sR += __shfl_xor(sR,off);
    sRE += __shfl_xor(sRE,off);
    sT += __shfl_xor(sT,off);
  }
  __shared__ float red[3][4];
  int wv = tid>>6;
  if ((tid&63)==0){ red[0][wv]=sR; red[1][wv]=sRE; red[2][wv]=sT; }
  __syncthreads();
  if (tid==0){
    rowR[m] = red[0][0]+red[0][1]+red[0][2]+red[0][3];
    if (mode&1) rowRE[m] = red[1][0]+red[1][1]+red[1][2]+red[1][3];
    if (mode&2) rowT[m]  = red[2][0]+red[2][1]+red[2][2]+red[2][3];
  }
}

__global__ void upd_col(float* aV, float* colC, int K, int first){
  int k = blockIdx.x*256+threadIdx.x;
  if (k<K){
    float s = colC[k];
    float p = first ? 1.0f : aV[k];
    aV[k] = p/(p*s + SK_EPS);
    colC[k] = 0.0f;
  }
}
__global__ void upd_row(float* bV, const float* rowR, int M, int first){
  int m = blockIdx.x*256+threadIdx.x;
  if (m<M){
    float R = rowR[m];
    float p = first ? 1.0f : bV[m];
    bV[m] = p/(p*R + SK_EPS);
  }
}
__global__ void fin_rows(float* bV, const float* rowR, const float* rowRE, const float* rowT,
                         float* sumQ, float* ttok, int M){
  int m = blockIdx.x*256+threadIdx.x;
  if (m<M){
    float p = bV[m], R = rowR[m];
    float b3 = p/(p*R + SK_EPS);
    bV[m] = b3;
    float sq = b3*R;
    sumQ[m] = sq;
    ttok[m] = logf(rowRE[m])*sq - b3*rowT[m]*INV_TT;
  }
}

// ---------------- final reduce ----------------
__global__ __launch_bounds__(1024) void finalize(const unsigned char* __restrict__ mask,
    const float* __restrict__ sexp, const float* __restrict__ sdot,
    const float* __restrict__ sumQ, const float* __restrict__ ttok,
    const unsigned* __restrict__ maxd, float* __restrict__ out, int M, int K){
  int tid = threadIdx.x;
  __shared__ int isBool;
  if (tid==0) isBool = 0;
  __syncthreads();
  int f = 0;
  for (int i=tid; i<M; i+=1024) if ((i&3) && mask[i]) f = 1;
  if (f) isBool = 1;
  __syncthreads();
  int ib = isBool;
  float cn=0.f, cc=0.f, ts=0.f, ks=0.f;
  for (int m=tid; m<M; m+=1024){
    int mk = ib ? (mask[m]!=0) : (((const int*)mask)[m]!=0);
    float pt = logf(sexp[m])*sumQ[m] - sdot[m]*INV_TS;
    if (mk){ cn += pt; cc += 1.0f; }
    ts += ttok[m];
  }
  for (int k=tid; k<K; k+=1024){
    float d = decf(maxd[k]);
    ks += logf(sqrtf(fmaxf(2.0f-2.0f*d, 0.0f)) + SK_EPS);
  }
  #pragma unroll
  for (int off=1; off<64; off<<=1){
    cn += __shfl_xor(cn,off); cc += __shfl_xor(cc,off);
    ts += __shfl_xor(ts,off); ks += __shfl_xor(ks,off);
  }
  __shared__ float red[4][16];
  int wv = tid>>6;
  if ((tid&63)==0){ red[0][wv]=cn; red[1][wv]=cc; red[2][wv]=ts; red[3][wv]=ks; }
  __syncthreads();
  if (tid==0){
    float CN=0,CC=0,TS=0,KS=0;
    for (int i=0;i<16;++i){ CN+=red[0][i]; CC+=red[1][i]; TS+=red[2][i]; KS+=red[3][i]; }
    out[0] = CN/fmaxf(CC,1.0f);
    out[1] = TS/(float)M;
    out[2] = -KS/(float)K;
  }
}

extern "C" void kernel_launch(void* const* d_in, const int* in_sizes, int n_in,
                              void* d_out, int out_size, void* d_ws, size_t ws_size,
                              hipStream_t stream){
  const float* teacher = (const float*)d_in[0];
  const float* student = (const float*)d_in[1];
  const unsigned char* mask = (const unsigned char*)d_in[2];
  const float* proto = (const float*)d_in[3];
  const int D = 768;
  const int M = in_sizes[0]/D;   // 8192
  const int K = in_sizes[3]/D;   // 8192
  float* out = (float*)d_out;

  char* ws = (char*)d_ws;
  size_t off = 0;
  auto alloc = [&](size_t bytes)->void*{ void* p = ws+off; off += (bytes+255)&~(size_t)255; return p; };
  u16* t_logits = (u16*)alloc((size_t)M*K*2);
  u16* t_hat    = (u16*)alloc((size_t)M*D*2);
  u16* s_hat    = (u16*)alloc((size_t)M*D*2);
  u16* w_bf     = (u16*)alloc((size_t)K*D*2);
  u16* w_hat    = (u16*)alloc((size_t)K*D*2);
  float* colC   = (float*)alloc((size_t)K*4);
  float* sexp   = (float*)alloc((size_t)M*4);
  float* sdot   = (float*)alloc((size_t)M*4);
  unsigned* maxd= (unsigned*)alloc((size_t)K*4);
  float* aV     = (float*)alloc((size_t)K*4);
  float* bV     = (float*)alloc((size_t)M*4);
  float* rowR   = (float*)alloc((size_t)M*4);
  float* rowRE  = (float*)alloc((size_t)M*4);
  float* rowT   = (float*)alloc((size_t)M*4);
  float* sumQ   = (float*)alloc((size_t)M*4);
  float* ttok   = (float*)alloc((size_t)M*4);

  hipMemsetAsync(colC, 0, (size_t)K*4, stream);
  hipMemsetAsync(sexp, 0, (size_t)M*4, stream);
  hipMemsetAsync(sdot, 0, (size_t)M*4, stream);
  hipMemsetAsync(maxd, 0, (size_t)K*4, stream);

  norm_cast<<<M, 192, 0, stream>>>(teacher, t_hat, nullptr, 1);
  norm_cast<<<M, 192, 0, stream>>>(student, s_hat, nullptr, 1);
  norm_cast<<<K, 192, 0, stream>>>(proto, w_bf, w_hat, 1);

  int nblk = (M/128)*(K/128);    // 4096
  gemm_bt<0><<<nblk, 256, 0, stream>>>(t_hat, w_bf, K, D, t_logits, colC,
                                       nullptr,nullptr,nullptr,nullptr,nullptr,nullptr);

  dim3 cgrid(K/2048, M/64);
  // SK iter 1 (col-sum fused above)
  upd_col<<<(K+255)/256, 256, 0, stream>>>(aV, colC, K, 1);
  sk_rowsum<<<M, 256, 0, stream>>>(t_logits, aV, rowR, rowRE, rowT, K, 1);
  upd_row<<<(M+255)/256, 256, 0, stream>>>(bV, rowR, M, 1);
  // SK iter 2
  sk_colsum<<<cgrid, 256, 0, stream>>>(t_logits, bV, colC, K, 1);
  upd_col<<<(K+255)/256, 256, 0, stream>>>(aV, colC, K, 0);
  sk_rowsum<<<M, 256, 0, stream>>>(t_logits, aV, rowR, rowRE, rowT, K, 0);
  upd_row<<<(M+255)/256, 256, 0, stream>>>(bV, rowR, M, 0);
  // SK iter 3
  sk_colsum<<<cgrid, 256, 0, stream>>>(t_logits, bV, colC, K, 1);
  upd_col<<<(K+255)/256, 256, 0, stream>>>(aV, colC, K, 0);
  sk_rowsum<<<M, 256, 0, stream>>>(t_logits, aV, rowR, rowRE, rowT, K, 2);
  fin_rows<<<(M+255)/256, 256, 0, stream>>>(bV, rowR, rowRE, rowT, sumQ, ttok, M);

  gemm_bt<1><<<nblk, 256, 0, stream>>>(s_hat, w_bf, K, D, nullptr, nullptr,
                                       t_logits, aV, bV, sexp, sdot, nullptr);
  gemm_bt<2><<<nblk, 256, 0, stream>>>(w_hat, w_hat, K, D, nullptr, nullptr,
                                       nullptr,nullptr,nullptr,nullptr,nullptr, maxd);

  finalize<<<1, 1024, 0, stream>>>(mask, sexp, sdot, sumQ, ttok, maxd, out, M, K);
}